// Round 1
// baseline (406.129 us; speedup 1.0000x reference)
//
#include <hip/hip_runtime.h>
#include <cstdint>

// ---------------------------------------------------------------------------
// CrossAttentionBlock: q/k/v proj (bf16 MFMA) -> flash attention -> o proj
// (+residual) -> LayerNorm.  B=2, SQ=1024, SKV=4096, E=1024, H=16, D=64.
// ---------------------------------------------------------------------------

typedef __bf16 bf16x8_t __attribute__((ext_vector_type(8)));
typedef float  f32x4_t  __attribute__((ext_vector_type(4)));

#define E_DIM 1024
#define NH    16
#define HD    64

__device__ __forceinline__ unsigned short f32_bf16(float f) {
    union { float f; unsigned int u; } v; v.f = f;
    unsigned int u = v.u;
    unsigned int r = (u + 0x7fffu + ((u >> 16) & 1u)) >> 16;  // RNE
    return (unsigned short)r;
}

// ---------------- cast fp32 -> bf16 (n multiple of 4) ----------------------
__global__ void cast_f32_bf16(const float* __restrict__ src,
                              unsigned short* __restrict__ dst, int n4) {
    int i = blockIdx.x * blockDim.x + threadIdx.x;
    if (i < n4) {
        float4 v = reinterpret_cast<const float4*>(src)[i];
        ushort4 o;
        o.x = f32_bf16(v.x); o.y = f32_bf16(v.y);
        o.z = f32_bf16(v.z); o.w = f32_bf16(v.w);
        reinterpret_cast<ushort4*>(dst)[i] = o;
    }
}

// ---------------- GEMM: C = A @ W^T + bias, scatter to [B,H,S,D] bf16 ------
// A: [M,1024] bf16 row-major, W: [1024,1024] bf16 row-major (row n = out col n)
#define BM 128
#define BN 128
#define BK 64
#define LDK 88   // padded LDS stride (176B: 44 banks -> only 2-way aliasing)

__global__ __launch_bounds__(256) void gemm_qkv(
    const unsigned short* __restrict__ A,
    const unsigned short* __restrict__ W,
    const float* __restrict__ bias,
    unsigned short* __restrict__ out,   // [B, NH, S, HD]
    int lgS)
{
    __shared__ __align__(16) unsigned short As[BM * LDK];
    __shared__ __align__(16) unsigned short Bs[BN * LDK];
    int tid  = threadIdx.x;
    int m0   = blockIdx.y * BM;
    int n0   = blockIdx.x * BN;
    int lane = tid & 63, wave = tid >> 6;
    int l15  = lane & 15, quad = lane >> 4;
    int wm   = (wave >> 1) * 64, wn = (wave & 1) * 64;

    f32x4_t acc[4][4];
#pragma unroll
    for (int i = 0; i < 4; i++)
#pragma unroll
        for (int j = 0; j < 4; j++) acc[i][j] = (f32x4_t)(0.f);

    for (int k0 = 0; k0 < 1024; k0 += BK) {
        __syncthreads();
#pragma unroll
        for (int i = 0; i < 4; i++) {
            int c = tid + i * 256;
            int row = c >> 3, col = (c & 7) << 3;
            *reinterpret_cast<uint4*>(&As[row * LDK + col]) =
                *reinterpret_cast<const uint4*>(&A[(m0 + row) * 1024 + k0 + col]);
            *reinterpret_cast<uint4*>(&Bs[row * LDK + col]) =
                *reinterpret_cast<const uint4*>(&W[(n0 + row) * 1024 + k0 + col]);
        }
        __syncthreads();
#pragma unroll
        for (int ks = 0; ks < 2; ks++) {
            bf16x8_t af[4], bf[4];
#pragma unroll
            for (int mi = 0; mi < 4; mi++)
                af[mi] = *reinterpret_cast<const bf16x8_t*>(
                    &As[(wm + mi * 16 + l15) * LDK + ks * 32 + quad * 8]);
#pragma unroll
            for (int ni = 0; ni < 4; ni++)
                bf[ni] = *reinterpret_cast<const bf16x8_t*>(
                    &Bs[(wn + ni * 16 + l15) * LDK + ks * 32 + quad * 8]);
#pragma unroll
            for (int mi = 0; mi < 4; mi++)
#pragma unroll
                for (int ni = 0; ni < 4; ni++)
                    acc[mi][ni] = __builtin_amdgcn_mfma_f32_16x16x32_bf16(
                        af[mi], bf[ni], acc[mi][ni], 0, 0, 0);
        }
    }
    int Smask = (1 << lgS) - 1;
#pragma unroll
    for (int mi = 0; mi < 4; mi++) {
#pragma unroll
        for (int ni = 0; ni < 4; ni++) {
            int n = n0 + wn + ni * 16 + l15;
            float bv = bias[n];
            int h = n >> 6, d = n & 63;
#pragma unroll
            for (int r = 0; r < 4; r++) {
                int mg = m0 + wm + mi * 16 + quad * 4 + r;
                int b = mg >> lgS, s = mg & Smask;
                out[(((b * NH + h) << lgS) + s) * HD + d] =
                    f32_bf16(acc[mi][ni][r] + bv);
            }
        }
    }
}

// ---------------- O-proj GEMM + bias + residual -> fp32 --------------------
__global__ __launch_bounds__(256) void gemm_oproj(
    const unsigned short* __restrict__ A,      // AO [2048,1024] bf16
    const unsigned short* __restrict__ W,      // Wo
    const float* __restrict__ bias,
    const float* __restrict__ resid,           // query fp32 [2048,1024]
    float* __restrict__ xout)                  // fp32 [2048,1024]
{
    __shared__ __align__(16) unsigned short As[BM * LDK];
    __shared__ __align__(16) unsigned short Bs[BN * LDK];
    int tid  = threadIdx.x;
    int m0   = blockIdx.y * BM;
    int n0   = blockIdx.x * BN;
    int lane = tid & 63, wave = tid >> 6;
    int l15  = lane & 15, quad = lane >> 4;
    int wm   = (wave >> 1) * 64, wn = (wave & 1) * 64;

    f32x4_t acc[4][4];
#pragma unroll
    for (int i = 0; i < 4; i++)
#pragma unroll
        for (int j = 0; j < 4; j++) acc[i][j] = (f32x4_t)(0.f);

    for (int k0 = 0; k0 < 1024; k0 += BK) {
        __syncthreads();
#pragma unroll
        for (int i = 0; i < 4; i++) {
            int c = tid + i * 256;
            int row = c >> 3, col = (c & 7) << 3;
            *reinterpret_cast<uint4*>(&As[row * LDK + col]) =
                *reinterpret_cast<const uint4*>(&A[(m0 + row) * 1024 + k0 + col]);
            *reinterpret_cast<uint4*>(&Bs[row * LDK + col]) =
                *reinterpret_cast<const uint4*>(&W[(n0 + row) * 1024 + k0 + col]);
        }
        __syncthreads();
#pragma unroll
        for (int ks = 0; ks < 2; ks++) {
            bf16x8_t af[4], bf[4];
#pragma unroll
            for (int mi = 0; mi < 4; mi++)
                af[mi] = *reinterpret_cast<const bf16x8_t*>(
                    &As[(wm + mi * 16 + l15) * LDK + ks * 32 + quad * 8]);
#pragma unroll
            for (int ni = 0; ni < 4; ni++)
                bf[ni] = *reinterpret_cast<const bf16x8_t*>(
                    &Bs[(wn + ni * 16 + l15) * LDK + ks * 32 + quad * 8]);
#pragma unroll
            for (int mi = 0; mi < 4; mi++)
#pragma unroll
                for (int ni = 0; ni < 4; ni++)
                    acc[mi][ni] = __builtin_amdgcn_mfma_f32_16x16x32_bf16(
                        af[mi], bf[ni], acc[mi][ni], 0, 0, 0);
        }
    }
#pragma unroll
    for (int mi = 0; mi < 4; mi++) {
#pragma unroll
        for (int ni = 0; ni < 4; ni++) {
            int n = n0 + wn + ni * 16 + l15;
            float bv = bias[n];
#pragma unroll
            for (int r = 0; r < 4; r++) {
                int mg = m0 + wm + mi * 16 + quad * 4 + r;
                xout[mg * 1024 + n] = acc[mi][ni][r] + bv + resid[mg * 1024 + n];
            }
        }
    }
}

// ---------------- flash attention ------------------------------------------
// grid (SQ/64, NH, B), block 256 (4 waves).  Each wave owns a 16-row q strip.
__global__ __launch_bounds__(256) void attn_kernel(
    const unsigned short* __restrict__ Q,   // [B,NH,1024,64]
    const unsigned short* __restrict__ K,   // [B,NH,4096,64]
    const unsigned short* __restrict__ V,   // [B,NH,4096,64]
    const int* __restrict__ mask,           // [B,4096]
    unsigned short* __restrict__ AO)        // [B,1024,1024] bf16
{
    __shared__ __align__(16) unsigned short Qs[64 * 88];
    __shared__ __align__(16) unsigned short Ks[64 * 88];
    __shared__ __align__(16) unsigned short Vt[64 * 88];  // [d][kv]
    __shared__ __align__(16) unsigned short Ps[64 * 88];  // 4 waves x 16 rows
    __shared__ float msk[64];

    int tid  = threadIdx.x;
    int lane = tid & 63, wave = tid >> 6;
    int l15  = lane & 15, quad = lane >> 4;
    int b = blockIdx.z, h = blockIdx.y, q0 = blockIdx.x * 64;

    const unsigned short* Qb = Q + ((b * NH + h) * 1024 + q0) * HD;
    const unsigned short* Kb = K + (b * NH + h) * 4096 * HD;
    const unsigned short* Vb = V + (b * NH + h) * 4096 * HD;
    const int* mb = mask + b * 4096;

#pragma unroll
    for (int i = 0; i < 2; i++) {
        int c = tid + i * 256;
        int row = c >> 3, col = (c & 7) << 3;
        *reinterpret_cast<uint4*>(&Qs[row * 88 + col]) =
            *reinterpret_cast<const uint4*>(&Qb[row * HD + col]);
    }

    float m_r[4], l_r[4];
    f32x4_t o_acc[4];
#pragma unroll
    for (int r = 0; r < 4; r++) { m_r[r] = -1e30f; l_r[r] = 0.f; }
#pragma unroll
    for (int ni = 0; ni < 4; ni++) o_acc[ni] = (f32x4_t)(0.f);

    for (int kt = 0; kt < 64; kt++) {
        int kv0 = kt * 64;
        __syncthreads();
#pragma unroll
        for (int i = 0; i < 2; i++) {
            int c = tid + i * 256;
            int row = c >> 3, col = (c & 7) << 3;
            *reinterpret_cast<uint4*>(&Ks[row * 88 + col]) =
                *reinterpret_cast<const uint4*>(&Kb[(kv0 + row) * HD + col]);
            uint4 vv = *reinterpret_cast<const uint4*>(&Vb[(kv0 + row) * HD + col]);
            const unsigned short* vs = reinterpret_cast<const unsigned short*>(&vv);
#pragma unroll
            for (int j = 0; j < 8; j++)
                Vt[(col + j) * 88 + row] = vs[j];
        }
        if (tid < 64) msk[tid] = mb[kv0 + tid] ? 0.f : -1e30f;
        __syncthreads();

        // ---- S = Q K^T (strip 16 x 64) ----
        f32x4_t s_acc[4];
#pragma unroll
        for (int ni = 0; ni < 4; ni++) s_acc[ni] = (f32x4_t)(0.f);
        bf16x8_t aq[2];
#pragma unroll
        for (int ks = 0; ks < 2; ks++)
            aq[ks] = *reinterpret_cast<const bf16x8_t*>(
                &Qs[(wave * 16 + l15) * 88 + ks * 32 + quad * 8]);
#pragma unroll
        for (int ni = 0; ni < 4; ni++)
#pragma unroll
            for (int ks = 0; ks < 2; ks++) {
                bf16x8_t bk = *reinterpret_cast<const bf16x8_t*>(
                    &Ks[(ni * 16 + l15) * 88 + ks * 32 + quad * 8]);
                s_acc[ni] = __builtin_amdgcn_mfma_f32_16x16x32_bf16(
                    aq[ks], bk, s_acc[ni], 0, 0, 0);
            }

        // ---- online softmax over this 64-wide tile ----
        float p[4][4];
        float tmax[4] = { -1e30f, -1e30f, -1e30f, -1e30f };
#pragma unroll
        for (int ni = 0; ni < 4; ni++) {
            float madd = msk[ni * 16 + l15];
#pragma unroll
            for (int r = 0; r < 4; r++) {
                float s = s_acc[ni][r] * 0.125f + madd;   // 1/sqrt(64)
                p[ni][r] = s;
                tmax[r] = fmaxf(tmax[r], s);
            }
        }
#pragma unroll
        for (int off = 1; off < 16; off <<= 1)
#pragma unroll
            for (int r = 0; r < 4; r++)
                tmax[r] = fmaxf(tmax[r], __shfl_xor(tmax[r], off, 64));

        float alpha[4], rowsum[4];
#pragma unroll
        for (int r = 0; r < 4; r++) {
            float mnew = fmaxf(m_r[r], tmax[r]);
            alpha[r] = __expf(m_r[r] - mnew);
            m_r[r] = mnew;
            rowsum[r] = 0.f;
        }
#pragma unroll
        for (int ni = 0; ni < 4; ni++)
#pragma unroll
            for (int r = 0; r < 4; r++) {
                float pe = __expf(p[ni][r] - m_r[r]);
                rowsum[r] += pe;
                Ps[(wave * 16 + quad * 4 + r) * 88 + ni * 16 + l15] = f32_bf16(pe);
            }
#pragma unroll
        for (int off = 1; off < 16; off <<= 1)
#pragma unroll
            for (int r = 0; r < 4; r++)
                rowsum[r] += __shfl_xor(rowsum[r], off, 64);
#pragma unroll
        for (int r = 0; r < 4; r++)
            l_r[r] = l_r[r] * alpha[r] + rowsum[r];

        // ---- O = alpha*O + P V  (P wave-private in LDS, no barrier needed) ----
        bf16x8_t ap[2];
#pragma unroll
        for (int ks = 0; ks < 2; ks++)
            ap[ks] = *reinterpret_cast<const bf16x8_t*>(
                &Ps[(wave * 16 + l15) * 88 + ks * 32 + quad * 8]);
#pragma unroll
        for (int ni = 0; ni < 4; ni++) {
            f32x4_t oo = o_acc[ni];
#pragma unroll
            for (int r = 0; r < 4; r++) oo[r] *= alpha[r];
#pragma unroll
            for (int ks = 0; ks < 2; ks++) {
                bf16x8_t bv = *reinterpret_cast<const bf16x8_t*>(
                    &Vt[(ni * 16 + l15) * 88 + ks * 32 + quad * 8]);
                oo = __builtin_amdgcn_mfma_f32_16x16x32_bf16(ap[ks], bv, oo, 0, 0, 0);
            }
            o_acc[ni] = oo;
        }
    }

#pragma unroll
    for (int ni = 0; ni < 4; ni++) {
        int col = h * HD + ni * 16 + l15;
#pragma unroll
        for (int r = 0; r < 4; r++) {
            int srow = q0 + wave * 16 + quad * 4 + r;
            AO[(b * 1024 + srow) * E_DIM + col] = f32_bf16(o_acc[ni][r] / l_r[r]);
        }
    }
}

// ---------------- LayerNorm over E=1024 ------------------------------------
__global__ __launch_bounds__(256) void ln_kernel(
    const float* __restrict__ x, const float* __restrict__ g,
    const float* __restrict__ be, float* __restrict__ out)
{
    __shared__ float red[8];
    int row = blockIdx.x, tid = threadIdx.x;
    float4 v = reinterpret_cast<const float4*>(x)[row * 256 + tid];
    float s  = v.x + v.y + v.z + v.w;
    float sq = v.x * v.x + v.y * v.y + v.z * v.z + v.w * v.w;
#pragma unroll
    for (int off = 32; off >= 1; off >>= 1) {
        s  += __shfl_xor(s,  off, 64);
        sq += __shfl_xor(sq, off, 64);
    }
    if ((tid & 63) == 0) { red[tid >> 6] = s; red[4 + (tid >> 6)] = sq; }
    __syncthreads();
    s  = red[0] + red[1] + red[2] + red[3];
    sq = red[4] + red[5] + red[6] + red[7];
    float mu  = s * (1.f / 1024.f);
    float var = sq * (1.f / 1024.f) - mu * mu;
    float rs  = rsqrtf(var + 1e-5f);
    int c = tid * 4;
    float4 o;
    o.x = (v.x - mu) * rs * g[c]     + be[c];
    o.y = (v.y - mu) * rs * g[c + 1] + be[c + 1];
    o.z = (v.z - mu) * rs * g[c + 2] + be[c + 2];
    o.w = (v.w - mu) * rs * g[c + 3] + be[c + 3];
    reinterpret_cast<float4*>(out)[row * 256 + tid] = o;
}

// ---------------------------------------------------------------------------
extern "C" void kernel_launch(void* const* d_in, const int* in_sizes, int n_in,
                              void* d_out, int out_size, void* d_ws, size_t ws_size,
                              hipStream_t stream) {
    const float* query     = (const float*)d_in[0];
    const float* key_value = (const float*)d_in[1];
    const int*   kv_mask   = (const int*)d_in[2];
    const float* Wq = (const float*)d_in[3];
    const float* bq = (const float*)d_in[4];
    const float* Wk = (const float*)d_in[5];
    const float* bk = (const float*)d_in[6];
    const float* Wv = (const float*)d_in[7];
    const float* bv = (const float*)d_in[8];
    const float* Wo = (const float*)d_in[9];
    const float* bo = (const float*)d_in[10];
    const float* ln_g = (const float*)d_in[11];
    const float* ln_b = (const float*)d_in[12];
    float* out = (float*)d_out;

    char* ws = (char*)d_ws;
    unsigned short* Xq  = (unsigned short*)(ws);                     // 4 MiB
    unsigned short* Xkv = (unsigned short*)(ws + (4ll  << 20));      // 16 MiB
    unsigned short* Wqb = (unsigned short*)(ws + (20ll << 20));      // 2 MiB
    unsigned short* Wkb = (unsigned short*)(ws + (22ll << 20));
    unsigned short* Wvb = (unsigned short*)(ws + (24ll << 20));
    unsigned short* Wob = (unsigned short*)(ws + (26ll << 20));
    unsigned short* Qh  = (unsigned short*)(ws + (28ll << 20));      // 4 MiB
    unsigned short* Kh  = (unsigned short*)(ws + (32ll << 20));      // 16 MiB
    unsigned short* Vh  = (unsigned short*)(ws + (48ll << 20));      // 16 MiB
    unsigned short* AO  = (unsigned short*)(ws + (64ll << 20));      // 4 MiB
    float*          Xr  = (float*)(ws + (68ll << 20));               // 8 MiB

    cast_f32_bf16<<<2048, 256, 0, stream>>>(query,     Xq,  512 * 1024);
    cast_f32_bf16<<<8192, 256, 0, stream>>>(key_value, Xkv, 2 * 1024 * 1024);
    cast_f32_bf16<<<1024, 256, 0, stream>>>(Wq, Wqb, 256 * 1024);
    cast_f32_bf16<<<1024, 256, 0, stream>>>(Wk, Wkb, 256 * 1024);
    cast_f32_bf16<<<1024, 256, 0, stream>>>(Wv, Wvb, 256 * 1024);
    cast_f32_bf16<<<1024, 256, 0, stream>>>(Wo, Wob, 256 * 1024);

    gemm_qkv<<<dim3(8, 16), 256, 0, stream>>>(Xq,  Wqb, bq, Qh, 10);
    gemm_qkv<<<dim3(8, 64), 256, 0, stream>>>(Xkv, Wkb, bk, Kh, 12);
    gemm_qkv<<<dim3(8, 64), 256, 0, stream>>>(Xkv, Wvb, bv, Vh, 12);

    attn_kernel<<<dim3(16, NH, 2), 256, 0, stream>>>(Qh, Kh, Vh, kv_mask, AO);

    gemm_oproj<<<dim3(8, 16), 256, 0, stream>>>(AO, Wob, bo, query, Xr);

    ln_kernel<<<2048, 256, 0, stream>>>(Xr, ln_g, ln_b, out);
}

// Round 2
// 321.346 us; speedup vs baseline: 1.2638x; 1.2638x over previous
//
#include <hip/hip_runtime.h>
#include <cstdint>

// ---------------------------------------------------------------------------
// CrossAttentionBlock: q/k/v proj (bf16 MFMA) -> flash attention (S^T form,
// in-register P transpose, KV-split) -> merge -> o proj (+residual) -> LN.
// B=2, SQ=1024, SKV=4096, E=1024, H=16, D=64.
// ---------------------------------------------------------------------------

typedef __bf16 bf16x8_t __attribute__((ext_vector_type(8)));
typedef float  f32x4_t  __attribute__((ext_vector_type(4)));

#define E_DIM 1024
#define NH    16
#define HD    64

__device__ __forceinline__ unsigned short f32_bf16(float f) {
    union { float f; unsigned int u; } v; v.f = f;
    unsigned int u = v.u;
    unsigned int r = (u + 0x7fffu + ((u >> 16) & 1u)) >> 16;  // RNE
    return (unsigned short)r;
}

__device__ __forceinline__ unsigned pack_bf16(float a, float b) {
    // hardware cvt via __bf16 cast (RNE on gfx950)
    __bf16 x = (__bf16)a, y = (__bf16)b;
    unsigned short ux = __builtin_bit_cast(unsigned short, x);
    unsigned short uy = __builtin_bit_cast(unsigned short, y);
    return (unsigned)ux | ((unsigned)uy << 16);
}

// ---------------- cast fp32 -> bf16 (n multiple of 4) ----------------------
__global__ void cast_f32_bf16(const float* __restrict__ src,
                              unsigned short* __restrict__ dst, int n4) {
    int i = blockIdx.x * blockDim.x + threadIdx.x;
    if (i < n4) {
        float4 v = reinterpret_cast<const float4*>(src)[i];
        ushort4 o;
        o.x = f32_bf16(v.x); o.y = f32_bf16(v.y);
        o.z = f32_bf16(v.z); o.w = f32_bf16(v.w);
        reinterpret_cast<ushort4*>(dst)[i] = o;
    }
}

// ---------------- GEMM: C = A @ W^T + bias -------------------------------
// mode 0: scatter to [B,H,S,D] bf16.  mode 1: scatter to [B,H,D,S] bf16 (V^T).
#define BM 128
#define BN 128
#define BK 64
#define LDK 88

__global__ __launch_bounds__(256) void gemm_qkv(
    const unsigned short* __restrict__ A,
    const unsigned short* __restrict__ W,
    const float* __restrict__ bias,
    unsigned short* __restrict__ out,
    int lgS, int vt_mode)
{
    __shared__ __align__(16) unsigned short As[BM * LDK];
    __shared__ __align__(16) unsigned short Bs[BN * LDK];
    int tid  = threadIdx.x;
    int m0   = blockIdx.y * BM;
    int n0   = blockIdx.x * BN;
    int lane = tid & 63, wave = tid >> 6;
    int l15  = lane & 15, quad = lane >> 4;
    int wm   = (wave >> 1) * 64, wn = (wave & 1) * 64;

    f32x4_t acc[4][4];
#pragma unroll
    for (int i = 0; i < 4; i++)
#pragma unroll
        for (int j = 0; j < 4; j++) acc[i][j] = (f32x4_t)(0.f);

    for (int k0 = 0; k0 < 1024; k0 += BK) {
        __syncthreads();
#pragma unroll
        for (int i = 0; i < 4; i++) {
            int c = tid + i * 256;
            int row = c >> 3, col = (c & 7) << 3;
            *reinterpret_cast<uint4*>(&As[row * LDK + col]) =
                *reinterpret_cast<const uint4*>(&A[(m0 + row) * 1024 + k0 + col]);
            *reinterpret_cast<uint4*>(&Bs[row * LDK + col]) =
                *reinterpret_cast<const uint4*>(&W[(n0 + row) * 1024 + k0 + col]);
        }
        __syncthreads();
#pragma unroll
        for (int ks = 0; ks < 2; ks++) {
            bf16x8_t af[4], bf[4];
#pragma unroll
            for (int mi = 0; mi < 4; mi++)
                af[mi] = *reinterpret_cast<const bf16x8_t*>(
                    &As[(wm + mi * 16 + l15) * LDK + ks * 32 + quad * 8]);
#pragma unroll
            for (int ni = 0; ni < 4; ni++)
                bf[ni] = *reinterpret_cast<const bf16x8_t*>(
                    &Bs[(wn + ni * 16 + l15) * LDK + ks * 32 + quad * 8]);
#pragma unroll
            for (int mi = 0; mi < 4; mi++)
#pragma unroll
                for (int ni = 0; ni < 4; ni++)
                    acc[mi][ni] = __builtin_amdgcn_mfma_f32_16x16x32_bf16(
                        af[mi], bf[ni], acc[mi][ni], 0, 0, 0);
        }
    }
    int Smask = (1 << lgS) - 1;
    if (!vt_mode) {
#pragma unroll
        for (int mi = 0; mi < 4; mi++) {
#pragma unroll
            for (int ni = 0; ni < 4; ni++) {
                int n = n0 + wn + ni * 16 + l15;
                float bv = bias[n];
                int h = n >> 6, d = n & 63;
#pragma unroll
                for (int r = 0; r < 4; r++) {
                    int mg = m0 + wm + mi * 16 + quad * 4 + r;
                    int b = mg >> lgS, s = mg & Smask;
                    out[(((b * NH + h) << lgS) + s) * HD + d] =
                        f32_bf16(acc[mi][ni][r] + bv);
                }
            }
        }
    } else {
        // V^T layout: out[((b*NH+h)*HD + d) << lgS | s], 4 consecutive s per thread
#pragma unroll
        for (int mi = 0; mi < 4; mi++) {
#pragma unroll
            for (int ni = 0; ni < 4; ni++) {
                int n = n0 + wn + ni * 16 + l15;
                float bv = bias[n];
                int h = n >> 6, d = n & 63;
                int mg0 = m0 + wm + mi * 16 + quad * 4;
                int b = mg0 >> lgS, s = mg0 & Smask;
                ushort4 w;
                w.x = f32_bf16(acc[mi][ni][0] + bv);
                w.y = f32_bf16(acc[mi][ni][1] + bv);
                w.z = f32_bf16(acc[mi][ni][2] + bv);
                w.w = f32_bf16(acc[mi][ni][3] + bv);
                *reinterpret_cast<ushort4*>(
                    &out[(((b * NH + h) * HD + d) << lgS) + s]) = w;
            }
        }
    }
}

// ---------------- O-proj GEMM + bias + residual -> fp32 --------------------
__global__ __launch_bounds__(256) void gemm_oproj(
    const unsigned short* __restrict__ A,
    const unsigned short* __restrict__ W,
    const float* __restrict__ bias,
    const float* __restrict__ resid,
    float* __restrict__ xout)
{
    __shared__ __align__(16) unsigned short As[BM * LDK];
    __shared__ __align__(16) unsigned short Bs[BN * LDK];
    int tid  = threadIdx.x;
    int m0   = blockIdx.y * BM;
    int n0   = blockIdx.x * BN;
    int lane = tid & 63, wave = tid >> 6;
    int l15  = lane & 15, quad = lane >> 4;
    int wm   = (wave >> 1) * 64, wn = (wave & 1) * 64;

    f32x4_t acc[4][4];
#pragma unroll
    for (int i = 0; i < 4; i++)
#pragma unroll
        for (int j = 0; j < 4; j++) acc[i][j] = (f32x4_t)(0.f);

    for (int k0 = 0; k0 < 1024; k0 += BK) {
        __syncthreads();
#pragma unroll
        for (int i = 0; i < 4; i++) {
            int c = tid + i * 256;
            int row = c >> 3, col = (c & 7) << 3;
            *reinterpret_cast<uint4*>(&As[row * LDK + col]) =
                *reinterpret_cast<const uint4*>(&A[(m0 + row) * 1024 + k0 + col]);
            *reinterpret_cast<uint4*>(&Bs[row * LDK + col]) =
                *reinterpret_cast<const uint4*>(&W[(n0 + row) * 1024 + k0 + col]);
        }
        __syncthreads();
#pragma unroll
        for (int ks = 0; ks < 2; ks++) {
            bf16x8_t af[4], bf[4];
#pragma unroll
            for (int mi = 0; mi < 4; mi++)
                af[mi] = *reinterpret_cast<const bf16x8_t*>(
                    &As[(wm + mi * 16 + l15) * LDK + ks * 32 + quad * 8]);
#pragma unroll
            for (int ni = 0; ni < 4; ni++)
                bf[ni] = *reinterpret_cast<const bf16x8_t*>(
                    &Bs[(wn + ni * 16 + l15) * LDK + ks * 32 + quad * 8]);
#pragma unroll
            for (int mi = 0; mi < 4; mi++)
#pragma unroll
                for (int ni = 0; ni < 4; ni++)
                    acc[mi][ni] = __builtin_amdgcn_mfma_f32_16x16x32_bf16(
                        af[mi], bf[ni], acc[mi][ni], 0, 0, 0);
        }
    }
#pragma unroll
    for (int mi = 0; mi < 4; mi++) {
#pragma unroll
        for (int ni = 0; ni < 4; ni++) {
            int n = n0 + wn + ni * 16 + l15;
            float bv = bias[n];
#pragma unroll
            for (int r = 0; r < 4; r++) {
                int mg = m0 + wm + mi * 16 + quad * 4 + r;
                xout[mg * 1024 + n] = acc[mi][ni][r] + bv + resid[mg * 1024 + n];
            }
        }
    }
}

// ---------------- flash attention, S^T form, KV-split ----------------------
// grid (SQ/64, NH, B*2). block 256 (4 waves, 16 q rows each).
// Computes S^T = K·Q^T tiles (kv on MFMA rows), softmax with 2-shuffle
// reductions, P transposed to the PV B-operand in-register via quad shuffles.
#define LKS 80    // Ks stride (u16): 128x64 tile
#define LVT 136   // Vt stride (u16): 64x128 tile
#define SCALE_L2E 0.1803368804f   // (1/8) * log2(e)

__global__ __launch_bounds__(256, 4) void attn_kernel(
    const unsigned short* __restrict__ Q,   // [B,NH,1024,64]
    const unsigned short* __restrict__ K,   // [B,NH,4096,64]
    const unsigned short* __restrict__ VT,  // [B,NH,64,4096]
    const int* __restrict__ mask,           // [B,4096]
    float* __restrict__ Osc,                // [(b*2+half)*NH+h][1024][64] fp32
    float* __restrict__ Ml)                 // [(b*2+half)*NH+h][1024] float2
{
    __shared__ __align__(16) unsigned short Ks[128 * LKS];
    __shared__ __align__(16) unsigned short Vt[64 * LVT];
    __shared__ __align__(16) float msk[128];

    int tid  = threadIdx.x;
    int lane = tid & 63, wave = tid >> 6;
    int l15  = lane & 15, quad = lane >> 4;
    int bz = blockIdx.z, b = bz >> 1, half = bz & 1;
    int h = blockIdx.y, q0 = blockIdx.x * 64;
    int kvbase = half * 2048;

    const unsigned short* Kb = K + (((long)(b * NH + h) * 4096) + kvbase) * HD;
    const unsigned short* Vb = VT + ((long)(b * NH + h) * HD) * 4096 + kvbase;
    const int* mb = mask + b * 4096 + kvbase;

    int qrow = q0 + wave * 16 + l15;
    const unsigned short* Qb = Q + ((long)((b * NH + h) * 1024) + qrow) * HD;
    bf16x8_t qf0 = *reinterpret_cast<const bf16x8_t*>(Qb + quad * 8);
    bf16x8_t qf1 = *reinterpret_cast<const bf16x8_t*>(Qb + 32 + quad * 8);

    float m_run = 0.f, l_run = 0.f;
    f32x4_t o[4];
#pragma unroll
    for (int di = 0; di < 4; di++) o[di] = (f32x4_t)(0.f);

    int srcA = ((quad & 1) * 2) * 16 + l15;   // source lanes for P transpose
    int srcB = srcA + 16;
    int qh = quad >> 1;                        // which mi this quad consumes

    for (int kt = 0; kt < 16; kt++) {
        int kv0 = kt * 128;
        __syncthreads();
#pragma unroll
        for (int i = 0; i < 4; i++) {           // K tile 128x64
            int c = tid + i * 256;
            int row = c >> 3, col = (c & 7) << 3;
            *reinterpret_cast<uint4*>(&Ks[row * LKS + col]) =
                *reinterpret_cast<const uint4*>(&Kb[(kv0 + row) * HD + col]);
        }
#pragma unroll
        for (int i = 0; i < 4; i++) {           // V^T tile 64x128
            int c = tid + i * 256;
            int row = c >> 4, col = (c & 15) << 3;
            *reinterpret_cast<uint4*>(&Vt[row * LVT + col]) =
                *reinterpret_cast<const uint4*>(&Vb[row * 4096 + kv0 + col]);
        }
        if (tid < 128) msk[tid] = mb[kv0 + tid] ? 0.f : -1e30f;
        __syncthreads();

        // ---- S^T tiles: C[kv][q], 8 tiles of 16 kv ----
        float se[8][4];
        float tm = -1e30f;
#pragma unroll
        for (int mi = 0; mi < 8; mi++) {
            f32x4_t s = (f32x4_t)(0.f);
            bf16x8_t a0 = *reinterpret_cast<const bf16x8_t*>(
                &Ks[(mi * 16 + l15) * LKS + quad * 8]);
            s = __builtin_amdgcn_mfma_f32_16x16x32_bf16(a0, qf0, s, 0, 0, 0);
            bf16x8_t a1 = *reinterpret_cast<const bf16x8_t*>(
                &Ks[(mi * 16 + l15) * LKS + 32 + quad * 8]);
            s = __builtin_amdgcn_mfma_f32_16x16x32_bf16(a1, qf1, s, 0, 0, 0);
            float4 mv = *reinterpret_cast<const float4*>(&msk[mi * 16 + quad * 4]);
#pragma unroll
            for (int r = 0; r < 4; r++) {
                float v = fmaf(s[r], SCALE_L2E, (&mv.x)[r]);
                se[mi][r] = v;
                tm = fmaxf(tm, v);
            }
        }
        tm = fmaxf(tm, __shfl_xor(tm, 16, 64));
        tm = fmaxf(tm, __shfl_xor(tm, 32, 64));
        float mnew = fmaxf(m_run, tm);
        float alpha = exp2f(m_run - mnew);
        m_run = mnew;

        float rs = 0.f;
        unsigned pk[8][2];
#pragma unroll
        for (int mi = 0; mi < 8; mi++) {
            float p0 = exp2f(se[mi][0] - m_run);
            float p1 = exp2f(se[mi][1] - m_run);
            float p2 = exp2f(se[mi][2] - m_run);
            float p3 = exp2f(se[mi][3] - m_run);
            rs += (p0 + p1) + (p2 + p3);
            pk[mi][0] = pack_bf16(p0, p1);
            pk[mi][1] = pack_bf16(p2, p3);
        }
        rs += __shfl_xor(rs, 16, 64);
        rs += __shfl_xor(rs, 32, 64);
        l_run = l_run * alpha + rs;
#pragma unroll
        for (int di = 0; di < 4; di++)
#pragma unroll
            for (int r = 0; r < 4; r++) o[di][r] *= alpha;

        // ---- PV: O^T[d][q] += V^T · P ----
#pragma unroll
        for (int c = 0; c < 4; c++) {
            int m0i = 2 * c, m1i = 2 * c + 1;
            unsigned xA0 = __shfl((int)pk[m0i][0], srcA, 64);
            unsigned xA1 = __shfl((int)pk[m0i][1], srcA, 64);
            unsigned xA2 = __shfl((int)pk[m0i][0], srcB, 64);
            unsigned xA3 = __shfl((int)pk[m0i][1], srcB, 64);
            unsigned xB0 = __shfl((int)pk[m1i][0], srcA, 64);
            unsigned xB1 = __shfl((int)pk[m1i][1], srcA, 64);
            unsigned xB2 = __shfl((int)pk[m1i][0], srcB, 64);
            unsigned xB3 = __shfl((int)pk[m1i][1], srcB, 64);
            union { uint4 u; bf16x8_t f; } bw;
            bw.u.x = qh ? xB0 : xA0;
            bw.u.y = qh ? xB1 : xA1;
            bw.u.z = qh ? xB2 : xA2;
            bw.u.w = qh ? xB3 : xA3;
#pragma unroll
            for (int di = 0; di < 4; di++) {
                bf16x8_t va = *reinterpret_cast<const bf16x8_t*>(
                    &Vt[(di * 16 + l15) * LVT + c * 32 + quad * 8]);
                o[di] = __builtin_amdgcn_mfma_f32_16x16x32_bf16(va, bw.f, o[di], 0, 0, 0);
            }
        }
    }

    // epilogue: store un-normalized O^T as [q][d] fp32 + (m,l)
    long obase = ((long)(bz * NH + h) * 1024 + qrow) * HD;
#pragma unroll
    for (int di = 0; di < 4; di++) {
        float4 w; w.x = o[di][0]; w.y = o[di][1]; w.z = o[di][2]; w.w = o[di][3];
        *reinterpret_cast<float4*>(&Osc[obase + di * 16 + quad * 4]) = w;
    }
    if (quad == 0) {
        float2* ml2 = reinterpret_cast<float2*>(Ml);
        ml2[(long)(bz * NH + h) * 1024 + qrow] = make_float2(m_run, l_run);
    }
}

// ---------------- merge the two KV halves ----------------------------------
__global__ __launch_bounds__(256) void attn_merge(
    const float* __restrict__ Osc, const float* __restrict__ Ml,
    unsigned short* __restrict__ AO)
{
    int row = blockIdx.x * 4 + (threadIdx.x >> 6);   // (b,h,q) 0..32767
    int d = threadIdx.x & 63;
    int b = row >> 14, hq = row & 16383;
    int h = hq >> 10, q = hq & 1023;
    long i0 = ((long)(b * 2 + 0) * NH + h) * 1024 + q;
    long i1 = ((long)(b * 2 + 1) * NH + h) * 1024 + q;
    const float2* ml2 = reinterpret_cast<const float2*>(Ml);
    float2 ml0 = ml2[i0], ml1 = ml2[i1];
    float M = fmaxf(ml0.x, ml1.x);
    float e0 = exp2f(ml0.x - M), e1 = exp2f(ml1.x - M);
    float L = ml0.y * e0 + ml1.y * e1;
    float v = (Osc[i0 * HD + d] * e0 + Osc[i1 * HD + d] * e1) / L;
    AO[((long)(b * 1024 + q)) * E_DIM + h * HD + d] = f32_bf16(v);
}

// ---------------- LayerNorm over E=1024 ------------------------------------
__global__ __launch_bounds__(256) void ln_kernel(
    const float* __restrict__ x, const float* __restrict__ g,
    const float* __restrict__ be, float* __restrict__ out)
{
    __shared__ float red[8];
    int row = blockIdx.x, tid = threadIdx.x;
    float4 v = reinterpret_cast<const float4*>(x)[row * 256 + tid];
    float s  = v.x + v.y + v.z + v.w;
    float sq = v.x * v.x + v.y * v.y + v.z * v.z + v.w * v.w;
#pragma unroll
    for (int off = 32; off >= 1; off >>= 1) {
        s  += __shfl_xor(s,  off, 64);
        sq += __shfl_xor(sq, off, 64);
    }
    if ((tid & 63) == 0) { red[tid >> 6] = s; red[4 + (tid >> 6)] = sq; }
    __syncthreads();
    s  = red[0] + red[1] + red[2] + red[3];
    sq = red[4] + red[5] + red[6] + red[7];
    float mu  = s * (1.f / 1024.f);
    float var = sq * (1.f / 1024.f) - mu * mu;
    float rs  = rsqrtf(var + 1e-5f);
    int c = tid * 4;
    float4 o;
    o.x = (v.x - mu) * rs * g[c]     + be[c];
    o.y = (v.y - mu) * rs * g[c + 1] + be[c + 1];
    o.z = (v.z - mu) * rs * g[c + 2] + be[c + 2];
    o.w = (v.w - mu) * rs * g[c + 3] + be[c + 3];
    reinterpret_cast<float4*>(out)[row * 256 + tid] = o;
}

// ---------------------------------------------------------------------------
extern "C" void kernel_launch(void* const* d_in, const int* in_sizes, int n_in,
                              void* d_out, int out_size, void* d_ws, size_t ws_size,
                              hipStream_t stream) {
    const float* query     = (const float*)d_in[0];
    const float* key_value = (const float*)d_in[1];
    const int*   kv_mask   = (const int*)d_in[2];
    const float* Wq = (const float*)d_in[3];
    const float* bq = (const float*)d_in[4];
    const float* Wk = (const float*)d_in[5];
    const float* bk = (const float*)d_in[6];
    const float* Wv = (const float*)d_in[7];
    const float* bv = (const float*)d_in[8];
    const float* Wo = (const float*)d_in[9];
    const float* bo = (const float*)d_in[10];
    const float* ln_g = (const float*)d_in[11];
    const float* ln_b = (const float*)d_in[12];
    float* out = (float*)d_out;

    char* ws = (char*)d_ws;
    unsigned short* Xq  = (unsigned short*)(ws);                     // 4 MiB
    unsigned short* Xkv = (unsigned short*)(ws + (4ll  << 20));      // 16 MiB
    unsigned short* Wqb = (unsigned short*)(ws + (20ll << 20));      // 2 MiB
    unsigned short* Wkb = (unsigned short*)(ws + (22ll << 20));
    unsigned short* Wvb = (unsigned short*)(ws + (24ll << 20));
    unsigned short* Wob = (unsigned short*)(ws + (26ll << 20));
    unsigned short* Qh  = (unsigned short*)(ws + (28ll << 20));      // 4 MiB
    unsigned short* Kh  = (unsigned short*)(ws + (32ll << 20));      // 16 MiB
    unsigned short* VTh = (unsigned short*)(ws + (48ll << 20));      // 16 MiB
    unsigned short* AO  = (unsigned short*)(ws + (64ll << 20));      // 4 MiB
    float*          Xr  = (float*)(ws + (68ll << 20));               // 8 MiB
    float*          Osc = (float*)(ws + (76ll << 20));               // 16 MiB
    float*          Ml  = (float*)(ws + (92ll << 20));               // 0.5 MiB

    cast_f32_bf16<<<2048, 256, 0, stream>>>(query,     Xq,  512 * 1024);
    cast_f32_bf16<<<8192, 256, 0, stream>>>(key_value, Xkv, 2 * 1024 * 1024);
    cast_f32_bf16<<<1024, 256, 0, stream>>>(Wq, Wqb, 256 * 1024);
    cast_f32_bf16<<<1024, 256, 0, stream>>>(Wk, Wkb, 256 * 1024);
    cast_f32_bf16<<<1024, 256, 0, stream>>>(Wv, Wvb, 256 * 1024);
    cast_f32_bf16<<<1024, 256, 0, stream>>>(Wo, Wob, 256 * 1024);

    gemm_qkv<<<dim3(8, 16), 256, 0, stream>>>(Xq,  Wqb, bq, Qh,  10, 0);
    gemm_qkv<<<dim3(8, 64), 256, 0, stream>>>(Xkv, Wkb, bk, Kh,  12, 0);
    gemm_qkv<<<dim3(8, 64), 256, 0, stream>>>(Xkv, Wvb, bv, VTh, 12, 1);

    attn_kernel<<<dim3(16, NH, 4), 256, 0, stream>>>(Qh, Kh, VTh, kv_mask, Osc, Ml);
    attn_merge<<<8192, 256, 0, stream>>>(Osc, Ml, AO);

    gemm_oproj<<<dim3(8, 16), 256, 0, stream>>>(AO, Wob, bo, query, Xr);

    ln_kernel<<<2048, 256, 0, stream>>>(Xr, ln_g, ln_b, out);
}

// Round 3
// 304.699 us; speedup vs baseline: 1.3329x; 1.0546x over previous
//
#include <hip/hip_runtime.h>
#include <cstdint>

// ---------------------------------------------------------------------------
// CrossAttentionBlock: q/k/v proj (bf16 MFMA, global_load_lds staging) ->
// flash attention (S^T form, in-register P transpose, KV-split, DMA staging)
// -> merge -> o proj (+residual) -> LayerNorm.
// B=2, SQ=1024, SKV=4096, E=1024, H=16, D=64.
// ---------------------------------------------------------------------------

typedef __bf16 bf16x8_t __attribute__((ext_vector_type(8)));
typedef float  f32x4_t  __attribute__((ext_vector_type(4)));

#define E_DIM 1024
#define NH    16
#define HD    64

__device__ __forceinline__ unsigned short f32_bf16(float f) {
    union { float f; unsigned int u; } v; v.f = f;
    unsigned int u = v.u;
    unsigned int r = (u + 0x7fffu + ((u >> 16) & 1u)) >> 16;  // RNE
    return (unsigned short)r;
}

__device__ __forceinline__ unsigned pack_bf16(float a, float b) {
    __bf16 x = (__bf16)a, y = (__bf16)b;
    unsigned short ux = __builtin_bit_cast(unsigned short, x);
    unsigned short uy = __builtin_bit_cast(unsigned short, y);
    return (unsigned)ux | ((unsigned)uy << 16);
}

// async global->LDS, 16B per lane; lds base must be wave-uniform
__device__ __forceinline__ void gld16(const unsigned short* g, unsigned short* l) {
    __builtin_amdgcn_global_load_lds(
        (const __attribute__((address_space(1))) unsigned int*)g,
        (__attribute__((address_space(3))) unsigned int*)l, 16, 0, 0);
}

// ---------------- fused fp32 -> bf16 casts (all 6 tensors) -----------------
__global__ void cast_all(const float* __restrict__ q, const float* __restrict__ kv,
                         const float* __restrict__ wq, const float* __restrict__ wk,
                         const float* __restrict__ wv, const float* __restrict__ wo,
                         unsigned short* __restrict__ Xq, unsigned short* __restrict__ Xkv,
                         unsigned short* __restrict__ Wqb, unsigned short* __restrict__ Wkb,
                         unsigned short* __restrict__ Wvb, unsigned short* __restrict__ Wob) {
    long i = (long)blockIdx.x * 256 + threadIdx.x;   // float4 index
    const float* src; unsigned short* dst; long off;
    if (i < 2621440) {
        if (i < 524288) { src = q;  dst = Xq;  off = i; }
        else            { src = kv; dst = Xkv; off = i - 524288; }
    } else {
        long j = i - 2621440;
        int w = (int)(j >> 18); off = j & 262143;
        src = (w == 0) ? wq : (w == 1) ? wk : (w == 2) ? wv : wo;
        dst = (w == 0) ? Wqb : (w == 1) ? Wkb : (w == 2) ? Wvb : Wob;
    }
    float4 v = reinterpret_cast<const float4*>(src)[off];
    ushort4 o;
    o.x = f32_bf16(v.x); o.y = f32_bf16(v.y);
    o.z = f32_bf16(v.z); o.w = f32_bf16(v.w);
    reinterpret_cast<ushort4*>(dst)[off] = o;
}

// ---------------- GEMM: C = A @ W^T + bias (m97-style staging) -------------
// LDS 128x64 bf16 unpadded, XOR-swizzled chunks: logical (row, chunk c) lives
// at position c ^ (row&7); staging lane-contiguous, reads bank-balanced.
#define BM 128
#define BN 128
#define BK 64

__global__ __launch_bounds__(256) void gemm_qkv(
    const unsigned short* __restrict__ A,
    const unsigned short* __restrict__ W,
    const float* __restrict__ bias,
    unsigned short* __restrict__ out,   // mode0: [B,H,S,D], mode1: [B,H,D,S]
    int lgS, int vt_mode)
{
    __shared__ __align__(16) unsigned short As[BM * BK];
    __shared__ __align__(16) unsigned short Bs[BN * BK];
    int tid  = threadIdx.x;
    int m0   = blockIdx.y * BM;
    int n0   = blockIdx.x * BN;
    int lane = tid & 63;
    int wvu  = __builtin_amdgcn_readfirstlane(tid >> 6);
    int l15  = lane & 15, quad = lane >> 4, x7 = l15 & 7;
    int wm   = ((tid >> 6) >> 1) * 64, wn = ((tid >> 6) & 1) * 64;

    f32x4_t acc[4][4];
#pragma unroll
    for (int i = 0; i < 4; i++)
#pragma unroll
        for (int j = 0; j < 4; j++) acc[i][j] = (f32x4_t)(0.f);

    for (int k0 = 0; k0 < 1024; k0 += BK) {
        __syncthreads();
#pragma unroll
        for (int i = 0; i < 4; i++) {
            int s = (i * 4 + wvu) * 64 + lane;
            int row = s >> 3, pcol = ((s & 7) ^ (row & 7)) << 3;
            gld16(&A[(long)(m0 + row) * 1024 + k0 + pcol], &As[(i * 4 + wvu) * 512]);
            gld16(&W[(long)(n0 + row) * 1024 + k0 + pcol], &Bs[(i * 4 + wvu) * 512]);
        }
        __syncthreads();
        const char* Ab = (const char*)As;
        const char* Bb = (const char*)Bs;
#pragma unroll
        for (int ks = 0; ks < 2; ks++) {
            int pos = (((ks << 2) + quad) ^ x7) << 4;
            bf16x8_t af[4], bf[4];
#pragma unroll
            for (int mi = 0; mi < 4; mi++)
                af[mi] = *reinterpret_cast<const bf16x8_t*>(
                    Ab + (wm + mi * 16 + l15) * 128 + pos);
#pragma unroll
            for (int ni = 0; ni < 4; ni++)
                bf[ni] = *reinterpret_cast<const bf16x8_t*>(
                    Bb + (wn + ni * 16 + l15) * 128 + pos);
#pragma unroll
            for (int mi = 0; mi < 4; mi++)
#pragma unroll
                for (int ni = 0; ni < 4; ni++)
                    acc[mi][ni] = __builtin_amdgcn_mfma_f32_16x16x32_bf16(
                        af[mi], bf[ni], acc[mi][ni], 0, 0, 0);
        }
    }
    int Smask = (1 << lgS) - 1;
    if (!vt_mode) {
#pragma unroll
        for (int mi = 0; mi < 4; mi++) {
#pragma unroll
            for (int ni = 0; ni < 4; ni++) {
                int n = n0 + wn + ni * 16 + l15;
                float bv = bias[n];
                int h = n >> 6, d = n & 63;
#pragma unroll
                for (int r = 0; r < 4; r++) {
                    int mg = m0 + wm + mi * 16 + quad * 4 + r;
                    int b = mg >> lgS, s = mg & Smask;
                    out[(((b * NH + h) << lgS) + s) * HD + d] =
                        f32_bf16(acc[mi][ni][r] + bv);
                }
            }
        }
    } else {
#pragma unroll
        for (int mi = 0; mi < 4; mi++) {
#pragma unroll
            for (int ni = 0; ni < 4; ni++) {
                int n = n0 + wn + ni * 16 + l15;
                float bv = bias[n];
                int h = n >> 6, d = n & 63;
                int mg0 = m0 + wm + mi * 16 + quad * 4;
                int b = mg0 >> lgS, s = mg0 & Smask;
                ushort4 w;
                w.x = f32_bf16(acc[mi][ni][0] + bv);
                w.y = f32_bf16(acc[mi][ni][1] + bv);
                w.z = f32_bf16(acc[mi][ni][2] + bv);
                w.w = f32_bf16(acc[mi][ni][3] + bv);
                *reinterpret_cast<ushort4*>(
                    &out[(((b * NH + h) * HD + d) << lgS) + s]) = w;
            }
        }
    }
}

// ---------------- O-proj GEMM + bias + residual -> fp32 --------------------
__global__ __launch_bounds__(256) void gemm_oproj(
    const unsigned short* __restrict__ A,
    const unsigned short* __restrict__ W,
    const float* __restrict__ bias,
    const float* __restrict__ resid,
    float* __restrict__ xout)
{
    __shared__ __align__(16) unsigned short As[BM * BK];
    __shared__ __align__(16) unsigned short Bs[BN * BK];
    int tid  = threadIdx.x;
    int m0   = blockIdx.y * BM;
    int n0   = blockIdx.x * BN;
    int lane = tid & 63;
    int wvu  = __builtin_amdgcn_readfirstlane(tid >> 6);
    int l15  = lane & 15, quad = lane >> 4, x7 = l15 & 7;
    int wm   = ((tid >> 6) >> 1) * 64, wn = ((tid >> 6) & 1) * 64;

    f32x4_t acc[4][4];
#pragma unroll
    for (int i = 0; i < 4; i++)
#pragma unroll
        for (int j = 0; j < 4; j++) acc[i][j] = (f32x4_t)(0.f);

    for (int k0 = 0; k0 < 1024; k0 += BK) {
        __syncthreads();
#pragma unroll
        for (int i = 0; i < 4; i++) {
            int s = (i * 4 + wvu) * 64 + lane;
            int row = s >> 3, pcol = ((s & 7) ^ (row & 7)) << 3;
            gld16(&A[(long)(m0 + row) * 1024 + k0 + pcol], &As[(i * 4 + wvu) * 512]);
            gld16(&W[(long)(n0 + row) * 1024 + k0 + pcol], &Bs[(i * 4 + wvu) * 512]);
        }
        __syncthreads();
        const char* Ab = (const char*)As;
        const char* Bb = (const char*)Bs;
#pragma unroll
        for (int ks = 0; ks < 2; ks++) {
            int pos = (((ks << 2) + quad) ^ x7) << 4;
            bf16x8_t af[4], bf[4];
#pragma unroll
            for (int mi = 0; mi < 4; mi++)
                af[mi] = *reinterpret_cast<const bf16x8_t*>(
                    Ab + (wm + mi * 16 + l15) * 128 + pos);
#pragma unroll
            for (int ni = 0; ni < 4; ni++)
                bf[ni] = *reinterpret_cast<const bf16x8_t*>(
                    Bb + (wn + ni * 16 + l15) * 128 + pos);
#pragma unroll
            for (int mi = 0; mi < 4; mi++)
#pragma unroll
                for (int ni = 0; ni < 4; ni++)
                    acc[mi][ni] = __builtin_amdgcn_mfma_f32_16x16x32_bf16(
                        af[mi], bf[ni], acc[mi][ni], 0, 0, 0);
        }
    }
#pragma unroll
    for (int mi = 0; mi < 4; mi++) {
#pragma unroll
        for (int ni = 0; ni < 4; ni++) {
            int n = n0 + wn + ni * 16 + l15;
            float bv = bias[n];
#pragma unroll
            for (int r = 0; r < 4; r++) {
                int mg = m0 + wm + mi * 16 + quad * 4 + r;
                xout[mg * 1024 + n] = acc[mi][ni][r] + bv + resid[mg * 1024 + n];
            }
        }
    }
}

// ---------------- flash attention, S^T form, KV-split ----------------------
// grid (SQ/64, NH, B*2). block 256 (4 waves, 16 q rows each).
// Ks: 128x64 bf16 unpadded, chunk swizzle ^(row&7).  Vt: 64x128, ^(row&15).
#define SCALE_L2E 0.1803368804f   // (1/8) * log2(e)

__global__ __launch_bounds__(256, 4) void attn_kernel(
    const unsigned short* __restrict__ Q,   // [B,NH,1024,64]
    const unsigned short* __restrict__ K,   // [B,NH,4096,64]
    const unsigned short* __restrict__ VT,  // [B,NH,64,4096]
    const int* __restrict__ mask,           // [B,4096]
    float* __restrict__ Osc,                // [(b*2+half)*NH+h][1024][64] fp32
    float* __restrict__ Ml)                 // [(b*2+half)*NH+h][1024] float2
{
    __shared__ __align__(16) unsigned short Ks[128 * 64];
    __shared__ __align__(16) unsigned short Vt[64 * 128];
    __shared__ __align__(16) float msk[128];

    int tid  = threadIdx.x;
    int lane = tid & 63;
    int wvu  = __builtin_amdgcn_readfirstlane(tid >> 6);
    int wave = tid >> 6;
    int l15  = lane & 15, quad = lane >> 4, x7 = l15 & 7;
    int bz = blockIdx.z, b = bz >> 1, half = bz & 1;
    int h = blockIdx.y, q0 = blockIdx.x * 64;
    int kvbase = half * 2048;

    const unsigned short* Kb = K + (((long)(b * NH + h) * 4096) + kvbase) * HD;
    const unsigned short* Vb = VT + ((long)(b * NH + h) * HD) * 4096 + kvbase;
    const int* mb = mask + b * 4096 + kvbase;

    int qrow = q0 + wave * 16 + l15;
    const unsigned short* Qb = Q + ((long)((b * NH + h) * 1024) + qrow) * HD;
    bf16x8_t qf0 = *reinterpret_cast<const bf16x8_t*>(Qb + quad * 8);
    bf16x8_t qf1 = *reinterpret_cast<const bf16x8_t*>(Qb + 32 + quad * 8);

    float m_run = 0.f, l_run = 0.f;
    f32x4_t o[4];
#pragma unroll
    for (int di = 0; di < 4; di++) o[di] = (f32x4_t)(0.f);

    int srcA = ((quad & 1) * 2) * 16 + l15;
    int srcB = srcA + 16;
    int qh = quad >> 1;

    const char* Kc = (const char*)Ks;
    const char* Vc = (const char*)Vt;

    for (int kt = 0; kt < 16; kt++) {
        int kv0 = kt * 128;
        __syncthreads();
#pragma unroll
        for (int i = 0; i < 4; i++) {
            // Ks: 1024 slots of 16B; slot s -> row s>>3, chunk (s&7)^(row&7)
            int s = (i * 4 + wvu) * 64 + lane;
            int row = s >> 3, pcol = ((s & 7) ^ (row & 7)) << 3;
            gld16(&Kb[(long)(kv0 + row) * HD + pcol], &Ks[(i * 4 + wvu) * 512]);
            // Vt: 1024 slots; slot s -> row s>>4, chunk (s&15)^(row&15)
            int rv = s >> 4, pv = ((s & 15) ^ (rv & 15)) << 3;
            gld16(&Vb[(long)rv * 4096 + kv0 + pv], &Vt[(i * 4 + wvu) * 512]);
        }
        if (tid < 128) msk[tid] = mb[kv0 + tid] ? 0.f : -1e30f;
        __syncthreads();

        // ---- S^T tiles: C[kv][q], 8 tiles of 16 kv ----
        float se[8][4];
        float tm = -1e30f;
#pragma unroll
        for (int mi = 0; mi < 8; mi++) {
            f32x4_t s = (f32x4_t)(0.f);
            int row = mi * 16 + l15;
            bf16x8_t a0 = *reinterpret_cast<const bf16x8_t*>(
                Kc + row * 128 + ((quad ^ x7) << 4));
            s = __builtin_amdgcn_mfma_f32_16x16x32_bf16(a0, qf0, s, 0, 0, 0);
            bf16x8_t a1 = *reinterpret_cast<const bf16x8_t*>(
                Kc + row * 128 + (((4 + quad) ^ x7) << 4));
            s = __builtin_amdgcn_mfma_f32_16x16x32_bf16(a1, qf1, s, 0, 0, 0);
            float4 mv = *reinterpret_cast<const float4*>(&msk[mi * 16 + quad * 4]);
#pragma unroll
            for (int r = 0; r < 4; r++) {
                float v = fmaf(s[r], SCALE_L2E, (&mv.x)[r]);
                se[mi][r] = v;
                tm = fmaxf(tm, v);
            }
        }
        tm = fmaxf(tm, __shfl_xor(tm, 16, 64));
        tm = fmaxf(tm, __shfl_xor(tm, 32, 64));
        float mnew = fmaxf(m_run, tm);
        float alpha = exp2f(m_run - mnew);
        m_run = mnew;

        float rs = 0.f;
        unsigned pk[8][2];
#pragma unroll
        for (int mi = 0; mi < 8; mi++) {
            float p0 = exp2f(se[mi][0] - m_run);
            float p1 = exp2f(se[mi][1] - m_run);
            float p2 = exp2f(se[mi][2] - m_run);
            float p3 = exp2f(se[mi][3] - m_run);
            rs += (p0 + p1) + (p2 + p3);
            pk[mi][0] = pack_bf16(p0, p1);
            pk[mi][1] = pack_bf16(p2, p3);
        }
        rs += __shfl_xor(rs, 16, 64);
        rs += __shfl_xor(rs, 32, 64);
        l_run = l_run * alpha + rs;
#pragma unroll
        for (int di = 0; di < 4; di++)
#pragma unroll
            for (int r = 0; r < 4; r++) o[di][r] *= alpha;

        // ---- PV: O^T[d][q] += V^T · P ----
#pragma unroll
        for (int c = 0; c < 4; c++) {
            int m0i = 2 * c, m1i = 2 * c + 1;
            unsigned xA0 = __shfl((int)pk[m0i][0], srcA, 64);
            unsigned xA1 = __shfl((int)pk[m0i][1], srcA, 64);
            unsigned xA2 = __shfl((int)pk[m0i][0], srcB, 64);
            unsigned xA3 = __shfl((int)pk[m0i][1], srcB, 64);
            unsigned xB0 = __shfl((int)pk[m1i][0], srcA, 64);
            unsigned xB1 = __shfl((int)pk[m1i][1], srcA, 64);
            unsigned xB2 = __shfl((int)pk[m1i][0], srcB, 64);
            unsigned xB3 = __shfl((int)pk[m1i][1], srcB, 64);
            union { uint4 u; bf16x8_t f; } bw;
            bw.u.x = qh ? xB0 : xA0;
            bw.u.y = qh ? xB1 : xA1;
            bw.u.z = qh ? xB2 : xA2;
            bw.u.w = qh ? xB3 : xA3;
#pragma unroll
            for (int di = 0; di < 4; di++) {
                int row = di * 16 + l15;
                bf16x8_t va = *reinterpret_cast<const bf16x8_t*>(
                    Vc + row * 256 + ((((c << 2) + quad) ^ l15) << 4));
                o[di] = __builtin_amdgcn_mfma_f32_16x16x32_bf16(va, bw.f, o[di], 0, 0, 0);
            }
        }
    }

    long obase = ((long)(bz * NH + h) * 1024 + qrow) * HD;
#pragma unroll
    for (int di = 0; di < 4; di++) {
        float4 w; w.x = o[di][0]; w.y = o[di][1]; w.z = o[di][2]; w.w = o[di][3];
        *reinterpret_cast<float4*>(&Osc[obase + di * 16 + quad * 4]) = w;
    }
    if (quad == 0) {
        float2* ml2 = reinterpret_cast<float2*>(Ml);
        ml2[(long)(bz * NH + h) * 1024 + qrow] = make_float2(m_run, l_run);
    }
}

// ---------------- merge the two KV halves ----------------------------------
__global__ __launch_bounds__(256) void attn_merge(
    const float* __restrict__ Osc, const float* __restrict__ Ml,
    unsigned short* __restrict__ AO)
{
    int row = blockIdx.x * 4 + (threadIdx.x >> 6);   // (b,h,q) 0..32767
    int d = threadIdx.x & 63;
    int b = row >> 14, hq = row & 16383;
    int h = hq >> 10, q = hq & 1023;
    long i0 = ((long)(b * 2 + 0) * NH + h) * 1024 + q;
    long i1 = ((long)(b * 2 + 1) * NH + h) * 1024 + q;
    const float2* ml2 = reinterpret_cast<const float2*>(Ml);
    float2 ml0 = ml2[i0], ml1 = ml2[i1];
    float M = fmaxf(ml0.x, ml1.x);
    float e0 = exp2f(ml0.x - M), e1 = exp2f(ml1.x - M);
    float L = ml0.y * e0 + ml1.y * e1;
    float v = (Osc[i0 * HD + d] * e0 + Osc[i1 * HD + d] * e1) / L;
    AO[((long)(b * 1024 + q)) * E_DIM + h * HD + d] = f32_bf16(v);
}

// ---------------- LayerNorm over E=1024 ------------------------------------
__global__ __launch_bounds__(256) void ln_kernel(
    const float* __restrict__ x, const float* __restrict__ g,
    const float* __restrict__ be, float* __restrict__ out)
{
    __shared__ float red[8];
    int row = blockIdx.x, tid = threadIdx.x;
    float4 v = reinterpret_cast<const float4*>(x)[row * 256 + tid];
    float s  = v.x + v.y + v.z + v.w;
    float sq = v.x * v.x + v.y * v.y + v.z * v.z + v.w * v.w;
#pragma unroll
    for (int off = 32; off >= 1; off >>= 1) {
        s  += __shfl_xor(s,  off, 64);
        sq += __shfl_xor(sq, off, 64);
    }
    if ((tid & 63) == 0) { red[tid >> 6] = s; red[4 + (tid >> 6)] = sq; }
    __syncthreads();
    s  = red[0] + red[1] + red[2] + red[3];
    sq = red[4] + red[5] + red[6] + red[7];
    float mu  = s * (1.f / 1024.f);
    float var = sq * (1.f / 1024.f) - mu * mu;
    float rs  = rsqrtf(var + 1e-5f);
    int c = tid * 4;
    float4 o;
    o.x = (v.x - mu) * rs * g[c]     + be[c];
    o.y = (v.y - mu) * rs * g[c + 1] + be[c + 1];
    o.z = (v.z - mu) * rs * g[c + 2] + be[c + 2];
    o.w = (v.w - mu) * rs * g[c + 3] + be[c + 3];
    reinterpret_cast<float4*>(out)[row * 256 + tid] = o;
}

// ---------------------------------------------------------------------------
extern "C" void kernel_launch(void* const* d_in, const int* in_sizes, int n_in,
                              void* d_out, int out_size, void* d_ws, size_t ws_size,
                              hipStream_t stream) {
    const float* query     = (const float*)d_in[0];
    const float* key_value = (const float*)d_in[1];
    const int*   kv_mask   = (const int*)d_in[2];
    const float* Wq = (const float*)d_in[3];
    const float* bq = (const float*)d_in[4];
    const float* Wk = (const float*)d_in[5];
    const float* bk = (const float*)d_in[6];
    const float* Wv = (const float*)d_in[7];
    const float* bv = (const float*)d_in[8];
    const float* Wo = (const float*)d_in[9];
    const float* bo = (const float*)d_in[10];
    const float* ln_g = (const float*)d_in[11];
    const float* ln_b = (const float*)d_in[12];
    float* out = (float*)d_out;

    char* ws = (char*)d_ws;
    unsigned short* Xq  = (unsigned short*)(ws);                     // 4 MiB
    unsigned short* Xkv = (unsigned short*)(ws + (4ll  << 20));      // 16 MiB
    unsigned short* Wqb = (unsigned short*)(ws + (20ll << 20));      // 2 MiB
    unsigned short* Wkb = (unsigned short*)(ws + (22ll << 20));
    unsigned short* Wvb = (unsigned short*)(ws + (24ll << 20));
    unsigned short* Wob = (unsigned short*)(ws + (26ll << 20));
    unsigned short* Qh  = (unsigned short*)(ws + (28ll << 20));      // 4 MiB
    unsigned short* Kh  = (unsigned short*)(ws + (32ll << 20));      // 16 MiB
    unsigned short* VTh = (unsigned short*)(ws + (48ll << 20));      // 16 MiB
    unsigned short* AO  = (unsigned short*)(ws + (64ll << 20));      // 4 MiB
    float*          Xr  = (float*)(ws + (68ll << 20));               // 8 MiB
    float*          Osc = (float*)(ws + (76ll << 20));               // 16 MiB
    float*          Ml  = (float*)(ws + (92ll << 20));               // 0.5 MiB

    cast_all<<<14336, 256, 0, stream>>>(query, key_value, Wq, Wk, Wv, Wo,
                                        Xq, Xkv, Wqb, Wkb, Wvb, Wob);

    gemm_qkv<<<dim3(8, 16), 256, 0, stream>>>(Xq,  Wqb, bq, Qh,  10, 0);
    gemm_qkv<<<dim3(8, 64), 256, 0, stream>>>(Xkv, Wkb, bk, Kh,  12, 0);
    gemm_qkv<<<dim3(8, 64), 256, 0, stream>>>(Xkv, Wvb, bv, VTh, 12, 1);

    attn_kernel<<<dim3(16, NH, 4), 256, 0, stream>>>(Qh, Kh, VTh, kv_mask, Osc, Ml);
    attn_merge<<<8192, 256, 0, stream>>>(Osc, Ml, AO);

    gemm_oproj<<<dim3(8, 16), 256, 0, stream>>>(AO, Wob, bo, query, Xr);

    ln_kernel<<<2048, 256, 0, stream>>>(Xr, ln_g, ln_b, out);
}